// Round 1
// baseline (221.075 us; speedup 1.0000x reference)
//
#include <hip/hip_runtime.h>

// Haar 3-level DWT, fully fused, EIGHT floats (two float4) per thread.
// x: [B=2048, L=16384] fp32
// out: concat(cA3[B,2048], cD3[B,2048], cD2[B,4096], cD1[B,8192]) fp32
//
// Thread u owns x[8u..8u+7]:
//   level1: 4 (a,d) pairs  -> cD1 float4 store at index u
//   level2: 2 (a,d) pairs  -> cD2 float2 store at index u
//   level3: 1 (a,d) pair   -> cA3/cD3 scalar stores at index u (full wave)
// No shuffles, no divergence; every output stream is a full-wave coalesced
// store. All loads/stores non-temporal (stream-once data, keep L2 free).
//
// Index algebra (row = u>>11, pos = u&2047):
//   cD1: row*8192 + pos*4 .. +3  == float4 index u
//   cD2: row*4096 + pos*2 .. +1  == float2 index u
//   cA3/cD3: row*2048 + pos      == scalar index u

#define HS 0.7071067811865476f

typedef float vf4 __attribute__((ext_vector_type(4)));
typedef float vf2 __attribute__((ext_vector_type(2)));

constexpr int B = 2048;
constexpr int L = 16384;
constexpr int UNITS8 = B * (L / 8);             // 4,194,304 8-float units
constexpr size_t OFF_CD3 = (size_t)B * 2048;    //  4,194,304
constexpr size_t OFF_CD2 = OFF_CD3 * 2;         //  8,388,608
constexpr size_t OFF_CD1 = OFF_CD2 + (size_t)B * 4096; // 16,777,216

__global__ __launch_bounds__(256) void haar3_kernel(const vf4* __restrict__ x4,
                                                    float* __restrict__ out) {
    const int u = blockIdx.x * 256 + threadIdx.x;   // 8-float unit index

    const vf4 v0 = __builtin_nontemporal_load(&x4[2 * u]);
    const vf4 v1 = __builtin_nontemporal_load(&x4[2 * u + 1]);

    // level 1
    const float a10 = HS * (v0.x + v0.y), d10 = HS * (v0.x - v0.y);
    const float a11 = HS * (v0.z + v0.w), d11 = HS * (v0.z - v0.w);
    const float a12 = HS * (v1.x + v1.y), d12 = HS * (v1.x - v1.y);
    const float a13 = HS * (v1.z + v1.w), d13 = HS * (v1.z - v1.w);
    // level 2
    const float a20 = HS * (a10 + a11), d20 = HS * (a10 - a11);
    const float a21 = HS * (a12 + a13), d21 = HS * (a12 - a13);
    // level 3
    const float a3 = HS * (a20 + a21), d3 = HS * (a20 - a21);

    // cD1: float4 at index u (16B/lane, 1KB/wave, coalesced)
    vf4 d1v; d1v.x = d10; d1v.y = d11; d1v.z = d12; d1v.w = d13;
    __builtin_nontemporal_store(d1v, ((vf4*)(out + OFF_CD1)) + u);
    // cD2: float2 at index u (8B/lane, coalesced)
    vf2 d2v; d2v.x = d20; d2v.y = d21;
    __builtin_nontemporal_store(d2v, ((vf2*)(out + OFF_CD2)) + u);
    // cA3 / cD3: scalar at index u (4B/lane, full-wave 256B contiguous)
    __builtin_nontemporal_store(a3, out + u);
    __builtin_nontemporal_store(d3, out + OFF_CD3 + u);
}

extern "C" void kernel_launch(void* const* d_in, const int* in_sizes, int n_in,
                              void* d_out, int out_size, void* d_ws, size_t ws_size,
                              hipStream_t stream) {
    const vf4* x4 = (const vf4*)d_in[0];
    float* out = (float*)d_out;
    constexpr int block = 256;
    constexpr int grid = UNITS8 / block;            // 16384 blocks
    haar3_kernel<<<grid, block, 0, stream>>>(x4, out);
}